// Round 2
// baseline (352.071 us; speedup 1.0000x reference)
//
#include <hip/hip_runtime.h>
#include <hip/hip_cooperative_groups.h>
#include <math.h>

namespace cg = cooperative_groups;

#define BB 16
#define CC 512
#define NTOK 4096   // h*w
#define SS 8
#define TT 128      // token tile
#define NTILES (NTOK / TT)       // 32
#define RSTRIDE 36  // padded stride (floats) per token-group in reduce buffer
#define ESTRIDE 136 // padded [s][t] stride for E tile in LDS

// native 16B vector type acceptable to __builtin_nontemporal_store
typedef float nfloat4 __attribute__((ext_vector_type(4)));

// ---------------------------------------------------------------------------
// Fused cooperative kernel. grid = BB*NTILES = 512 blocks (2/CU, LDS 58 KB),
// 256 threads.
// Phase 1: E[t][s] = exp(sum_c x*WkT) for this block's 128 tokens, kept in
//          LDS; per-(b,tile,s) exp-sum -> esum_p via AGENT-scope atomic store
//          (per-XCD L2 is not coherent; plain stores can be read stale).
// grid.sync()
// Phase 2: l[s] = sum over tiles (agent-scope atomic loads); w = (E/l)
//          L1-renormed over s; out = relu(x + w.WvT), x re-read (L3-hot),
//          non-temporal stores.
// wbuf time-shares WkT (phase 1) and Wv (phase 2): fused LDS = 58 KB.
// ---------------------------------------------------------------------------
__global__ __launch_bounds__(256) void k_fused(const float* __restrict__ x,
                                               const float* __restrict__ Wk,
                                               const float* __restrict__ Wv,
                                               float* __restrict__ esum_p,
                                               float* __restrict__ out) {
    __shared__ float wbuf[CC * SS];                       // 16 KB (WkT then Wv)
    __shared__ float red[8 * 32 * RSTRIDE];               // 36 KB (reused ph2)
    __shared__ __align__(16) float Es[SS * ESTRIDE];      // 4.25 KB
    __shared__ float esum[4 * SS];
    __shared__ float invl_s[SS];

    const int tid   = threadIdx.x;
    const int tn    = tid & 31;
    const int tc    = tid >> 5;               // 0..7
    const int blk   = blockIdx.x;
    const int b     = blk >> 5;
    const int ntile = blk & 31;
    const int n0    = ntile * TT + tn * 4;

    for (int k = tid; k < CC * SS; k += 256) {
        int s = k >> 9;
        int c = k & (CC - 1);
        wbuf[c * SS + s] = Wk[k];             // WkT: [c][s]
    }
    __syncthreads();

    // ---- phase 1: logits ----------------------------------------------------
    float acc[4][SS];
#pragma unroll
    for (int i = 0; i < 4; ++i)
#pragma unroll
        for (int s = 0; s < SS; ++s) acc[i][s] = 0.f;

    const float* xb = x + (size_t)b * CC * NTOK + n0;
#pragma unroll 8
    for (int k = 0; k < CC / 8; ++k) {        // 64 iters, 8 float4 loads in flight
        int c = tc + k * 8;
        float4 x4 = *(const float4*)(xb + (size_t)c * NTOK);
        const float* wk = &wbuf[c * SS];
#pragma unroll
        for (int s = 0; s < SS; ++s) {
            float w = wk[s];
            acc[0][s] += x4.x * w;
            acc[1][s] += x4.y * w;
            acc[2][s] += x4.z * w;
            acc[3][s] += x4.w * w;
        }
    }

    // partials: 16B-aligned region per thread -> ds_write_b128
    float4* myred = (float4*)&red[tc * (32 * RSTRIDE) + tn * RSTRIDE];
#pragma unroll
    for (int i = 0; i < 4; ++i) {
        myred[i * 2]     = make_float4(acc[i][0], acc[i][1], acc[i][2], acc[i][3]);
        myred[i * 2 + 1] = make_float4(acc[i][4], acc[i][5], acc[i][6], acc[i][7]);
    }
    __syncthreads();

    // reduce 1024 outputs (128 tok x 8 s) over 8 partials; exp(); keep in LDS.
    // s = flat&7 = tid&7 (constant per thread across j). No max-subtraction:
    // logits ~ N(0,1) (Wk scaled 1/sqrt(c)), exp() safe in fp32.
    float es = 0.f;
#pragma unroll
    for (int j = 0; j < 4; ++j) {
        int flat = tid + j * 256;
        int tnp  = flat >> 5;
        int rem  = flat & 31;
        float v = 0.f;
#pragma unroll
        for (int t = 0; t < 8; ++t) v += red[t * (32 * RSTRIDE) + tnp * RSTRIDE + rem];
        float e = __expf(v);
        Es[(tid & 7) * ESTRIDE + (flat >> 3)] = e;   // [s][token]
        es += e;
    }
    // reduce es across lanes sharing lane&7 (same s)
    es += __shfl_down(es, 8, 64);
    es += __shfl_down(es, 16, 64);
    es += __shfl_down(es, 32, 64);
    const int lane = tid & 63, wave = tid >> 6;
    if (lane < SS) esum[wave * SS + lane] = es;
    __syncthreads();
    if (tid < SS) {
        float t = esum[tid] + esum[SS + tid] + esum[2 * SS + tid] + esum[3 * SS + tid];
        // AGENT scope: coherent across XCDs (plain store can be read stale)
        __hip_atomic_store(&esum_p[(b * NTILES + ntile) * SS + tid], t,
                           __ATOMIC_RELEASE, __HIP_MEMORY_SCOPE_AGENT);
    }
    cg::this_grid().sync();

    // ---- phase 2: denominators + output ------------------------------------
    // wbuf phase-1 reads all completed before the pre-sync barrier; reload Wv.
    for (int k = tid; k < CC * SS; k += 256) wbuf[k] = Wv[k];   // [c][s]
    // gather all 32 tiles' partial sums for this b (256 floats), reuse red.
    // relaxed AGENT atomic load: reads coherence point, bypasses stale L2.
    red[tid] = __hip_atomic_load(&esum_p[b * (NTILES * SS) + tid],
                                 __ATOMIC_RELAXED, __HIP_MEMORY_SCOPE_AGENT);
    __syncthreads();
    if (tid < SS) {
        float t = 0.f;
#pragma unroll
        for (int j = 0; j < NTILES; ++j) t += red[j * SS + tid];
        invl_s[tid] = 1.0f / t;
    }
    __syncthreads();

    // this thread's 4 tokens: E from LDS
    float w[4][SS];
#pragma unroll
    for (int s = 0; s < SS; ++s) {
        float iv = invl_s[s];
        float4 ev = *(const float4*)&Es[s * ESTRIDE + tn * 4];
        w[0][s] = ev.x * iv;
        w[1][s] = ev.y * iv;
        w[2][s] = ev.z * iv;
        w[3][s] = ev.w * iv;
    }
#pragma unroll
    for (int i = 0; i < 4; ++i) {
        float rs = 0.f;
#pragma unroll
        for (int s = 0; s < SS; ++s) rs += w[i][s];
        float inv = 1.0f / (1e-9f + rs);
#pragma unroll
        for (int s = 0; s < SS; ++s) w[i][s] *= inv;
    }

    // x re-read (L3-hot from phase 1); output stores NON-TEMPORAL (write-only)
    const size_t xbase = (size_t)b * CC * NTOK + n0;
#pragma unroll 8
    for (int k = 0; k < CC / 8; ++k) {        // 64 iters, all 512 c
        int c = tc + k * 8;
        const float* xp = x + xbase + (size_t)c * NTOK;
        float4 x4 = *(const float4*)xp;
        const float* wvc = &wbuf[c * SS];
        float o0 = 0.f, o1 = 0.f, o2 = 0.f, o3 = 0.f;
#pragma unroll
        for (int s = 0; s < SS; ++s) {
            float vv = wvc[s];
            o0 += w[0][s] * vv;
            o1 += w[1][s] * vv;
            o2 += w[2][s] * vv;
            o3 += w[3][s] * vv;
        }
        nfloat4 y;
        y.x = fmaxf(x4.x + o0, 0.f);
        y.y = fmaxf(x4.y + o1, 0.f);
        y.z = fmaxf(x4.z + o2, 0.f);
        y.w = fmaxf(x4.w + o3, 0.f);
        __builtin_nontemporal_store(y, (nfloat4*)(out + xbase + (size_t)c * NTOK));
    }
}

// ---------------------------------------------------------------------------
// Fallback path (proven at 261 us): two plain kernels via workspace E buffer.
// ---------------------------------------------------------------------------
__global__ __launch_bounds__(256) void k_logits(const float* __restrict__ x,
                                                const float* __restrict__ Wk,
                                                float* __restrict__ E,
                                                float* __restrict__ esum_p) {
    __shared__ float wkT[CC * SS];            // [c][s], 16 KB
    __shared__ float red[8 * 32 * RSTRIDE];   // 36 KB
    __shared__ float esum[4 * SS];
    const int tid   = threadIdx.x;
    const int tn    = tid & 31;
    const int tc    = tid >> 5;
    const int blk   = blockIdx.x;
    const int b     = blk >> 5;
    const int ntile = blk & 31;
    const int n0    = ntile * TT + tn * 4;

    for (int k = tid; k < CC * SS; k += 256) {
        int s = k >> 9;
        int c = k & (CC - 1);
        wkT[c * SS + s] = Wk[k];
    }
    __syncthreads();

    float acc[4][SS];
#pragma unroll
    for (int i = 0; i < 4; ++i)
#pragma unroll
        for (int s = 0; s < SS; ++s) acc[i][s] = 0.f;

    const float* xb = x + (size_t)b * CC * NTOK + n0;
#pragma unroll 8
    for (int k = 0; k < CC / 8; ++k) {
        int c = tc + k * 8;
        float4 x4 = *(const float4*)(xb + (size_t)c * NTOK);
        const float* wk = &wkT[c * SS];
#pragma unroll
        for (int s = 0; s < SS; ++s) {
            float w = wk[s];
            acc[0][s] += x4.x * w;
            acc[1][s] += x4.y * w;
            acc[2][s] += x4.z * w;
            acc[3][s] += x4.w * w;
        }
    }

    float4* myred = (float4*)&red[tc * (32 * RSTRIDE) + tn * RSTRIDE];
#pragma unroll
    for (int i = 0; i < 4; ++i) {
        myred[i * 2]     = make_float4(acc[i][0], acc[i][1], acc[i][2], acc[i][3]);
        myred[i * 2 + 1] = make_float4(acc[i][4], acc[i][5], acc[i][6], acc[i][7]);
    }
    __syncthreads();

    float* outb = E + ((size_t)b * NTOK + (size_t)ntile * TT) * SS;
    float es = 0.f;
#pragma unroll
    for (int j = 0; j < 4; ++j) {
        int flat = tid + j * 256;
        int tnp  = flat >> 5;
        int rem  = flat & 31;
        float v = 0.f;
#pragma unroll
        for (int t = 0; t < 8; ++t) v += red[t * (32 * RSTRIDE) + tnp * RSTRIDE + rem];
        float e = __expf(v);
        outb[flat] = e;
        es += e;
    }
    es += __shfl_down(es, 8, 64);
    es += __shfl_down(es, 16, 64);
    es += __shfl_down(es, 32, 64);
    const int lane = tid & 63, wave = tid >> 6;
    if (lane < SS) esum[wave * SS + lane] = es;
    __syncthreads();
    if (tid < SS) {
        float t = esum[tid] + esum[SS + tid] + esum[2 * SS + tid] + esum[3 * SS + tid];
        esum_p[(b * NTILES + ntile) * SS + tid] = t;
    }
}

__global__ __launch_bounds__(256) void k_out(const float* __restrict__ x,
                                             const float* __restrict__ Wv,
                                             const float* __restrict__ E,
                                             const float* __restrict__ esum_p,
                                             float* __restrict__ out) {
    __shared__ float wv[CC * SS];
    __shared__ float ep[NTILES * SS];
    __shared__ float invl_s[SS];
    const int tid   = threadIdx.x;
    const int tn    = tid & 31;
    const int tc    = tid >> 5;
    const int blk   = blockIdx.x;
    const int b     = blk >> 6;
    const int rest  = blk & 63;
    const int ntile = rest >> 1;
    const int chalf = rest & 1;
    const int n0    = ntile * TT + tn * 4;

    ep[tid] = esum_p[b * (NTILES * SS) + tid];
    for (int k = tid; k < CC * SS; k += 256) wv[k] = Wv[k];
    __syncthreads();
    if (tid < SS) {
        float t = 0.f;
#pragma unroll
        for (int j = 0; j < NTILES; ++j) t += ep[j * SS + tid];
        invl_s[tid] = 1.0f / t;
    }
    __syncthreads();

    float invl[SS];
#pragma unroll
    for (int s = 0; s < SS; ++s) invl[s] = invl_s[s];

    const float* lg = E + ((size_t)b * NTOK + n0) * SS;
    float w[4][SS];
#pragma unroll
    for (int i = 0; i < 4; ++i) {
        float4 p0 = *(const float4*)(lg + i * 8);
        float4 p1 = *(const float4*)(lg + i * 8 + 4);
        float e[SS] = {p0.x, p0.y, p0.z, p0.w, p1.x, p1.y, p1.z, p1.w};
        float rs = 0.f;
#pragma unroll
        for (int s = 0; s < SS; ++s) {
            float p = e[s] * invl[s];
            w[i][s] = p;
            rs += p;
        }
        float inv = 1.0f / (1e-9f + rs);
#pragma unroll
        for (int s = 0; s < SS; ++s) w[i][s] *= inv;
    }

    const size_t xbase = (size_t)b * CC * NTOK + n0;
#pragma unroll 8
    for (int k = 0; k < CC / 16; ++k) {
        int c = chalf * (CC / 2) + tc + k * 8;
        const float* xp = x + xbase + (size_t)c * NTOK;
        float4 x4 = *(const float4*)xp;
        const float* wvc = &wv[c * SS];
        float o0 = 0.f, o1 = 0.f, o2 = 0.f, o3 = 0.f;
#pragma unroll
        for (int s = 0; s < SS; ++s) {
            float vv = wvc[s];
            o0 += w[0][s] * vv;
            o1 += w[1][s] * vv;
            o2 += w[2][s] * vv;
            o3 += w[3][s] * vv;
        }
        nfloat4 y;
        y.x = fmaxf(x4.x + o0, 0.f);
        y.y = fmaxf(x4.y + o1, 0.f);
        y.z = fmaxf(x4.z + o2, 0.f);
        y.w = fmaxf(x4.w + o3, 0.f);
        __builtin_nontemporal_store(y, (nfloat4*)(out + xbase + (size_t)c * NTOK));
    }
}

// ---------------------------------------------------------------------------
extern "C" void kernel_launch(void* const* d_in, const int* in_sizes, int n_in,
                              void* d_out, int out_size, void* d_ws, size_t ws_size,
                              hipStream_t stream) {
    const float* x  = (const float*)d_in[0];   // [16][512][64][64]
    const float* Wk = (const float*)d_in[1];   // [8][512]
    const float* Wv = (const float*)d_in[2];   // [512][8]
    float* outp = (float*)d_out;

    float* esum_p = (float*)d_ws;                          // 4096 floats
    float* E      = esum_p + (size_t)BB * NTILES * SS;     // 2 MB (fallback only)

    void* args[] = {(void*)&x, (void*)&Wk, (void*)&Wv, (void*)&esum_p, (void*)&outp};
    hipError_t e = hipLaunchCooperativeKernel((void*)k_fused, dim3(BB * NTILES),
                                              dim3(256), args, 0, stream);
    if (e != hipSuccess) {
        // proven two-kernel path
        k_logits<<<BB * NTILES, 256, 0, stream>>>(x, Wk, E, esum_p);
        k_out<<<BB * NTILES * 2, 256, 0, stream>>>(x, Wv, E, esum_p, outp);
    }
}

// Round 3
// 260.559 us; speedup vs baseline: 1.3512x; 1.3512x over previous
//
#include <hip/hip_runtime.h>
#include <math.h>

#define BB 16
#define CC 512
#define NTOK 4096   // h*w
#define SS 8
#define TT 128      // token tile (k_out)
#define NTILES (NTOK / TT)       // 32 (k_out)
#define TT1 64      // token tile (k_logits)
#define NT1 (NTOK / TT1)         // 64 (k_logits)
#define RSTRIDE1 20 // padded stride (floats) per (tc,tn) in reduce buffer (16+4)

// native 16B vector type acceptable to __builtin_nontemporal_store
typedef float nfloat4 __attribute__((ext_vector_type(4)));

// ---------------------------------------------------------------------------
// Kernel 1: E[b][n][s] = exp(sum_c x[b][c][n]*Wk[s][c]);
//           esum_p[b][nt][s] = sum_{n in tile} E
// v2: TT1=64 tokens/block, 2 tokens/thread (float2), grid = BB*64 = 1024
//     blocks = 4/CU (16 waves/CU, was 2/CU & 8 waves in v1 -> latency-bound at
//     1.5 TB/s). red shrinks 36->20 KB so LDS 36.3 KB fits 4 blocks/CU.
//     unroll 16 keeps 16 float2 loads (128 B/lane) in flight.
// No max-subtraction: logits ~ N(0,1) (Wk scaled 1/sqrt(c)), exp() safe fp32.
// ---------------------------------------------------------------------------
__global__ __launch_bounds__(256) void k_logits(const float* __restrict__ x,
                                                const float* __restrict__ Wk,
                                                float* __restrict__ E,
                                                float* __restrict__ esum_p) {
    __shared__ float wkT[CC * SS];              // [c][s], 16 KB
    __shared__ float red[8 * 32 * RSTRIDE1];    // [tc][tn][i*8+s], 20 KB
    __shared__ float esum[4 * SS];
    const int tid   = threadIdx.x;
    const int tn    = tid & 31;                 // token-pair group 0..31
    const int tc    = tid >> 5;                 // 0..7, c = tc + 8k
    const int blk   = blockIdx.x;
    const int b     = blk >> 6;
    const int ntile = blk & 63;
    const int n0    = ntile * TT1 + tn * 2;

    for (int k = tid; k < CC * SS; k += 256) {
        int s = k >> 9;
        int c = k & (CC - 1);
        wkT[c * SS + s] = Wk[k];
    }
    __syncthreads();

    float acc[2][SS];
#pragma unroll
    for (int i = 0; i < 2; ++i)
#pragma unroll
        for (int s = 0; s < SS; ++s) acc[i][s] = 0.f;

    const float* xb = x + (size_t)b * CC * NTOK + n0;
#pragma unroll 16
    for (int k = 0; k < CC / 8; ++k) {          // 64 iters, 16 float2 in flight
        int c = tc + k * 8;
        float2 x2 = *(const float2*)(xb + (size_t)c * NTOK);
        const float* wk = &wkT[c * SS];
#pragma unroll
        for (int s = 0; s < SS; ++s) {
            float w = wk[s];
            acc[0][s] += x2.x * w;
            acc[1][s] += x2.y * w;
        }
    }

    // partials: 16 floats per thread, 16B-aligned (stride 20 floats = 80 B)
    float4* myred = (float4*)&red[tc * (32 * RSTRIDE1) + tn * RSTRIDE1];
    myred[0] = make_float4(acc[0][0], acc[0][1], acc[0][2], acc[0][3]);
    myred[1] = make_float4(acc[0][4], acc[0][5], acc[0][6], acc[0][7]);
    myred[2] = make_float4(acc[1][0], acc[1][1], acc[1][2], acc[1][3]);
    myred[3] = make_float4(acc[1][4], acc[1][5], acc[1][6], acc[1][7]);
    __syncthreads();

    // reduce 512 outputs (64 tok x 8 s) over 8 partials; exp(); fuse exp-sum.
    // flat = tnp*16 + i*8 + s  ->  s = flat&7 = tid&7 (constant per thread).
    float* outb = E + ((size_t)b * NTOK + (size_t)ntile * TT1) * SS;
    float es = 0.f;
#pragma unroll
    for (int j = 0; j < 2; ++j) {
        int flat = tid + j * 256;
        int tnp  = flat >> 4;
        int rem  = flat & 15;
        float v = 0.f;
#pragma unroll
        for (int t = 0; t < 8; ++t)
            v += red[t * (32 * RSTRIDE1) + tnp * RSTRIDE1 + rem];
        float e = __expf(v);
        outb[flat] = e;                         // coalesced
        es += e;
    }
    // reduce across lanes sharing lane&7 (same s)
    es += __shfl_down(es, 8, 64);
    es += __shfl_down(es, 16, 64);
    es += __shfl_down(es, 32, 64);
    const int lane = tid & 63, wave = tid >> 6;
    if (lane < SS) esum[wave * SS + lane] = es;
    __syncthreads();
    if (tid < SS) {
        float t = esum[tid] + esum[SS + tid] + esum[2 * SS + tid] + esum[3 * SS + tid];
        esum_p[(b * NT1 + ntile) * SS + tid] = t;   // distinct slot per block
    }
}

// ---------------------------------------------------------------------------
// Kernel 2: w[n,s] = E/l, L1-renorm over s; out = relu(x + sum_s w*Wv[c,s])
// grid = BB*64 = 1024 blocks (4/CU), 256 threads. 128-token tiles, c halved.
// x read is L3-hot (134 MB < 256 MB L3, fetched by k_logits). Output stores
// NON-TEMPORAL: out is write-only, keep x/E lines in cache.
// ---------------------------------------------------------------------------
__global__ __launch_bounds__(256) void k_out(const float* __restrict__ x,
                                             const float* __restrict__ Wv,
                                             const float* __restrict__ E,
                                             const float* __restrict__ esum_p,
                                             float* __restrict__ out) {
    __shared__ float wv[CC * SS];             // 16 KB
    __shared__ float ep[NT1 * SS];            // 512 partials for this b
    __shared__ float invl_s[SS];
    const int tid   = threadIdx.x;
    const int tn    = tid & 31;
    const int tc    = tid >> 5;               // 0..7
    const int blk   = blockIdx.x;
    const int b     = blk >> 6;
    const int rest  = blk & 63;
    const int ntile = rest >> 1;
    const int chalf = rest & 1;
    const int n0    = ntile * TT + tn * 4;

    ep[tid]       = esum_p[b * (NT1 * SS) + tid];          // 512 coalesced
    ep[tid + 256] = esum_p[b * (NT1 * SS) + 256 + tid];
    for (int k = tid; k < CC * SS; k += 256) wv[k] = Wv[k];
    __syncthreads();
    if (tid < SS) {
        float t = 0.f;
#pragma unroll
        for (int j = 0; j < NT1; ++j) t += ep[j * SS + tid];
        invl_s[tid] = 1.0f / t;
    }
    __syncthreads();

    float invl[SS];
#pragma unroll
    for (int s = 0; s < SS; ++s) invl[s] = invl_s[s];

    // this thread's 4 tokens: 32 consecutive E floats
    const float* lg = E + ((size_t)b * NTOK + n0) * SS;
    float w[4][SS];
#pragma unroll
    for (int i = 0; i < 4; ++i) {
        float4 p0 = *(const float4*)(lg + i * 8);
        float4 p1 = *(const float4*)(lg + i * 8 + 4);
        float e[SS] = {p0.x, p0.y, p0.z, p0.w, p1.x, p1.y, p1.z, p1.w};
        float rs = 0.f;
#pragma unroll
        for (int s = 0; s < SS; ++s) {
            float p = e[s] * invl[s];
            w[i][s] = p;
            rs += p;
        }
        float inv = 1.0f / (1e-9f + rs);
#pragma unroll
        for (int s = 0; s < SS; ++s) w[i][s] *= inv;
    }

    const size_t xbase = (size_t)b * CC * NTOK + n0;
#pragma unroll 8
    for (int k = 0; k < CC / 16; ++k) {       // 32 iters, 8 in flight
        int c = chalf * (CC / 2) + tc + k * 8;
        const float* xp = x + xbase + (size_t)c * NTOK;
        float4 x4 = *(const float4*)xp;
        const float* wvc = &wv[c * SS];
        float o0 = 0.f, o1 = 0.f, o2 = 0.f, o3 = 0.f;
#pragma unroll
        for (int s = 0; s < SS; ++s) {
            float vv = wvc[s];
            o0 += w[0][s] * vv;
            o1 += w[1][s] * vv;
            o2 += w[2][s] * vv;
            o3 += w[3][s] * vv;
        }
        nfloat4 y;
        y.x = fmaxf(x4.x + o0, 0.f);
        y.y = fmaxf(x4.y + o1, 0.f);
        y.z = fmaxf(x4.z + o2, 0.f);
        y.w = fmaxf(x4.w + o3, 0.f);
        __builtin_nontemporal_store(y, (nfloat4*)(out + xbase + (size_t)c * NTOK));
    }
}

// ---------------------------------------------------------------------------
extern "C" void kernel_launch(void* const* d_in, const int* in_sizes, int n_in,
                              void* d_out, int out_size, void* d_ws, size_t ws_size,
                              hipStream_t stream) {
    const float* x  = (const float*)d_in[0];   // [16][512][64][64]
    const float* Wk = (const float*)d_in[1];   // [8][512]
    const float* Wv = (const float*)d_in[2];   // [512][8]
    float* outp = (float*)d_out;

    float* esum_p = (float*)d_ws;                          // 16*64*8 = 8192 floats
    float* E      = esum_p + (size_t)BB * NT1 * SS;        // 2 MB

    k_logits<<<BB * NT1, 256, 0, stream>>>(x, Wk, E, esum_p);
    k_out<<<BB * NTILES * 2, 256, 0, stream>>>(x, Wv, E, esum_p, outp);
}